// Round 10
// baseline (577.661 us; speedup 1.0000x reference)
//
#include <hip/hip_runtime.h>
#include <stdint.h>
#include <stddef.h>

// ---- problem constants ----
#define BWIN 2048
#define NTOK 49
#define CDIM 384
#define HNUM 12
#define HD   32
#define MTOT (BWIN * NTOK)          // 100352 rows = 392 * 256
#define LOG2E 1.4426950408889634f
// q scale folded with log2(e): logits come out of MFMA in log2 domain
#define QSCALE ((float)(0.17677669529663687 * 1.4426950408889634))

typedef __attribute__((ext_vector_type(8))) short short8;   // 8 bf16 (4 VGPRs)
typedef __attribute__((ext_vector_type(4))) float floatx4;  // MFMA acc

__device__ __forceinline__ unsigned short f2bf(float f) {
    union { float f; unsigned u; } v; v.f = f;
    unsigned u = v.u;
    u = u + 0x7fffu + ((u >> 16) & 1u);   // round-to-nearest-even
    return (unsigned short)(u >> 16);
}

// async global->LDS, 16 B per lane; LDS dest = wave-uniform base + lane*16
__device__ __forceinline__ void gload16(const void* g, void* l) {
    __builtin_amdgcn_global_load_lds(
        (const __attribute__((address_space(1))) void*)g,
        (__attribute__((address_space(3))) void*)l, 16, 0, 0);
}

// =====================================================================
// Kernel 0: fp32 -> bf16 pre-convert (x, qkv_w, proj_w), 2048 elems/block
// =====================================================================
#define XBLK  18816   // 100352*384 / 2048
#define WQBLK 216     // 3*384*384 / 2048
#define WPBLK 72      // 384*384   / 2048
__global__ __launch_bounds__(256) void convert_kernel(
    const float* __restrict__ x, const float* __restrict__ wq,
    const float* __restrict__ wp, unsigned short* __restrict__ xbf,
    unsigned short* __restrict__ wqbf, unsigned short* __restrict__ wpbf)
{
    int bid = blockIdx.x;
    const float* src; unsigned short* dst; size_t base;
    if (bid < XBLK)              { src = x;  dst = xbf;  base = (size_t)bid * 2048; }
    else if (bid < XBLK + WQBLK) { src = wq; dst = wqbf; base = (size_t)(bid - XBLK) * 2048; }
    else                         { src = wp; dst = wpbf; base = (size_t)(bid - XBLK - WQBLK) * 2048; }
    const size_t i = base + (size_t)threadIdx.x * 8;
    float4 a = *(const float4*)(src + i);
    float4 b = *(const float4*)(src + i + 4);
    unsigned short o[8] = {f2bf(a.x), f2bf(a.y), f2bf(a.z), f2bf(a.w),
                           f2bf(b.x), f2bf(b.y), f2bf(b.z), f2bf(b.w)};
    *(uint4*)(dst + i) = *(uint4*)o;
}

// =====================================================================
// Kernel 0b: combined bias table in MFMA accumulator fragment order.
// =====================================================================
__global__ __launch_bounds__(256) void bias_kernel(
    const float* __restrict__ mask, const float* __restrict__ rpb,
    float* __restrict__ cb)
{
    const int bm = blockIdx.x, h = blockIdx.y;
    const int tid = threadIdx.x;
    const int w = tid >> 6, lane = tid & 63;
    const int cg = lane & 15, rg = lane >> 4;
    const int rbase = 16 * w + (rg << 2);
    const float* mk = mask + (size_t)bm * (NTOK * NTOK);
    float o[16];
    #pragma unroll
    for (int j = 0; j < 4; ++j) {
        const int col = 16 * j + cg;
        const bool vc = col < NTOK;
        int yj = 0, xj = 0;
        if (vc) { yj = col / 7; xj = col - yj * 7; }
        #pragma unroll
        for (int r = 0; r < 4; ++r) {
            const int row = rbase + r;
            float v = -1e30f;
            if (vc && row < NTOK) {
                const int yi = row / 7, xi = row - yi * 7;
                const int rel = (yi - yj + 6) * 13 + (xi - xj + 6);
                v = (rpb[rel * HNUM + h] + mk[row * NTOK + col]) * LOG2E;
            }
            o[4 * j + r] = v;
        }
    }
    float* dst = cb + ((size_t)bm * HNUM + h) * 4096 + (size_t)tid * 16;
    #pragma unroll
    for (int j = 0; j < 4; ++j)
        *(float4*)(dst + 4 * j) = *(const float4*)(o + 4 * j);
}

// =====================================================================
// Kernel 1: qkv = xbf @ wqbf^T + qkv_b -> scattered bf16 [3][B][H][N][hd]
// NEW: BM=256 x BN=128 tile, 512 threads (8 waves, 4M x 2N of 64x64).
// Rationale: qkv was latency-bound at 2.3 blocks/CU (28% occ, no pipe
// >35%). 72KB LDS -> 2 blocks x 8 waves = 16 waves/CU (1.7x TLP), half
// the block prologues/epilogues. Same 3-buffer counted-vmcnt pipeline
// (3 loads/wave/tile -> steady vmcnt(3)), same XOR swizzle (periodic per
// 16-row issue group), same per-wave fragment work and epilogue.
// =====================================================================
__global__ __launch_bounds__(512) void qkv_kernel(
    const unsigned short* __restrict__ a, const unsigned short* __restrict__ b,
    const float* __restrict__ bias, unsigned short* __restrict__ outq)
{
    __shared__ __align__(16) unsigned short lA[3][256 * 32];   // 16KB/buf
    __shared__ __align__(16) unsigned short lB[3][128 * 32];   // 8KB/buf

    const int tid = threadIdx.x;
    const int lane = tid & 63, w = tid >> 6;     // w in [0,8)

    // XCD-chunked swizzle: 3528 blocks, 3528/8 = 441 per XCD (exact).
    // 9 consecutive wg share one 256-row A panel on the same XCD.
    const int bid = blockIdx.x;
    const int wg = (bid & 7) * 441 + (bid >> 3);
    const int tN = (wg % 9) * 128;
    const int tM = (wg / 9) * 256;

    // staging source pre-swizzle (per 16-row / 1KB issue block)
    const int X = (lane << 4) ^ (((lane >> 3) & 7) << 4);
    const int scol = (X & 63) >> 1;
    // A: wave w stages rows [32w, 32w+32) in two 16-row issues
    const int srowA = (w << 5) + (X >> 6);
    const unsigned short* gA = a + (size_t)(tM + srowA) * CDIM + scol;
    // B: wave w stages rows [16w, 16w+16) in one issue
    const int srowB = (w << 4) + (X >> 6);
    const unsigned short* gB = b + (size_t)(tN + srowB) * CDIM + scol;

    const int wm = (w & 3) << 6;        // 4 M-waves: 0,64,128,192
    const int wn = (w >> 2) << 6;       // 2 N-waves: 0,64
    const int cg = lane & 15, rg = lane >> 4;

    floatx4 acc[4][4];
    #pragma unroll
    for (int i = 0; i < 4; ++i)
        #pragma unroll
        for (int j = 0; j < 4; ++j) acc[i][j] = (floatx4){0.f, 0.f, 0.f, 0.f};

    // swizzled fragment byte offsets (within one tile buffer)
    int offA[4], offB[4];
    #pragma unroll
    for (int i = 0; i < 4; ++i) {
        const int rowA = wm + 16 * i + cg;
        const int sA = (rowA << 6) + (rg << 4);
        offA[i] = sA ^ (((sA >> 7) & 7) << 4);
        const int rowB = wn + 16 * i + cg;
        const int sB = (rowB << 6) + (rg << 4);
        offB[i] = sB ^ (((sB >> 7) & 7) << 4);
    }

    // 3 gload_lds per wave per tile: 2 for A, 1 for B
    #define STAGE_Q(BUF, K0) do {                                          \
        unsigned short* _lAb = &lA[(BUF)][w << 10];                        \
        unsigned short* _lBb = &lB[(BUF)][w << 9];                         \
        gload16(gA + (K0),              _lAb);                             \
        gload16(gA + (K0) + 16 * CDIM,  _lAb + 512);                       \
        gload16(gB + (K0),              _lBb);                             \
    } while (0)

    STAGE_Q(0, 0);
    STAGE_Q(1, 32);

    #pragma unroll
    for (int t = 0; t < 12; ++t) {
        // steady state: tiles t,t+1 in flight (6 loads); drain oldest 3.
        if (t < 11) asm volatile("s_waitcnt vmcnt(3)" ::: "memory");
        else        asm volatile("s_waitcnt vmcnt(0)" ::: "memory");
        __builtin_amdgcn_s_barrier();
        __builtin_amdgcn_sched_barrier(0);

        const int bufA = (t % 3) * 16384;
        const int bufB = (t % 3) * 8192;
        short8 af[4], bfr[4];
        #pragma unroll
        for (int i = 0; i < 4; ++i)
            af[i] = *(const short8*)((const char*)lA + bufA + offA[i]);
        #pragma unroll
        for (int j = 0; j < 4; ++j)
            bfr[j] = *(const short8*)((const char*)lB + bufB + offB[j]);

        if (t < 10) STAGE_Q((t + 2) % 3, (t + 2) * 32);   // buf (t-1)%3: safe

        __builtin_amdgcn_s_setprio(1);
        #pragma unroll
        for (int i = 0; i < 4; ++i)
            #pragma unroll
            for (int j = 0; j < 4; ++j)
                acc[i][j] = __builtin_amdgcn_mfma_f32_16x16x32_bf16(af[i], bfr[j], acc[i][j], 0, 0, 0);
        __builtin_amdgcn_s_setprio(0);
    }
    #undef STAGE_Q

    // epilogue: hoisted index math (per wave identical to 128-tile case)
    const int r0 = tM + wm + (rg << 2);
    float bv[4], sc[4];
    size_t cjo[4];
    #pragma unroll
    for (int j = 0; j < 4; ++j) {
        const int col = tN + wn + 16 * j + cg;
        bv[j] = bias[col];
        const int which = col / CDIM;
        const int rem = col - which * CDIM;
        const int h = rem >> 5, d = rem & 31;
        sc[j] = (which == 0) ? QSCALE : 1.0f;
        cjo[j] = (size_t)which * (BWIN * HNUM * NTOK * HD)
               + (size_t)h * (NTOK * HD) + d;
    }
    #pragma unroll
    for (int i = 0; i < 4; ++i) {
        #pragma unroll
        for (int r = 0; r < 4; ++r) {
            const int row = r0 + 16 * i + r;
            const int bb = row / NTOK;
            const int n = row - bb * NTOK;
            const size_t ro = (size_t)bb * (HNUM * NTOK * HD) + (size_t)n * HD;
            #pragma unroll
            for (int j = 0; j < 4; ++j)
                outq[cjo[j] + ro] = f2bf((acc[i][j][r] + bv[j]) * sc[j]);
        }
    }
}

// =====================================================================
// Kernel 2: MFMA attention — verified structure + XCD-locality decode
// (neutral but harmless; keeps per-XCD cb working set L2-resident)
// =====================================================================
__global__ __launch_bounds__(256) void attn_kernel(
    const unsigned short* __restrict__ qkv, const float* __restrict__ cb,
    unsigned short* __restrict__ outa)
{
    __shared__ __align__(16) unsigned short lq[64][40];
    __shared__ __align__(16) unsigned short lk[64][40];
    __shared__ __align__(16) unsigned short lvt[32][72];
    __shared__ __align__(16) unsigned short lp[64][72];

    const int bid = blockIdx.x;
    const int xcd = bid & 7;
    const int u = (bid >> 3) & 7;
    const int t2 = bid >> 6;
    const int h = t2 % 12;
    const int v = t2 / 12;
    const int b = u + 8 * xcd + 64 * v;

    const int tid = threadIdx.x;
    const size_t WHICH = (size_t)BWIN * HNUM * NTOK * HD;
    const size_t base = ((size_t)b * HNUM + h) * (NTOK * HD);

    const float* cbp = cb + ((size_t)(b & 63) * HNUM + h) * 4096 + (size_t)tid * 16;
    floatx4 z[4];
    #pragma unroll
    for (int j = 0; j < 4; ++j) z[j] = *(const floatx4*)(cbp + 4 * j);

    for (int e = tid; e < 1152; e += 256)
        ((unsigned*)&lvt[0][0])[e] = 0u;
    if (tid < 240) {
        const int r = 49 + (tid >> 4), c = (tid & 15) * 2;
        *(unsigned*)&lq[r][c] = 0u;
        *(unsigned*)&lk[r][c] = 0u;
    }
    uint4 vreg;
    if (tid < 196) {
        const int n = tid >> 2, d = (tid & 3) * 8;
        *(uint4*)&lq[n][d] = *(const uint4*)(qkv + base + tid * 8);
        *(uint4*)&lk[n][d] = *(const uint4*)(qkv + base + WHICH + tid * 8);
        vreg = *(const uint4*)(qkv + base + 2 * WHICH + tid * 8);
    }
    __syncthreads();

    if (tid < 196) {
        const int n = tid >> 2, d0 = (tid & 3) * 8;
        const unsigned short* vp = (const unsigned short*)&vreg;
        #pragma unroll
        for (int jj = 0; jj < 8; ++jj)
            lvt[d0 + jj][n] = vp[jj];
    }

    const int w = tid >> 6, lane = tid & 63;
    const int cg = lane & 15;
    const int rg = lane >> 4;
    const int rbase = 16 * w + rg * 4;

    short8 aq = *(const short8*)&lq[16 * w + cg][rg * 8];
    floatx4 s[4];
    #pragma unroll
    for (int j = 0; j < 4; ++j) {
        short8 bk = *(const short8*)&lk[16 * j + cg][rg * 8];
        s[j] = __builtin_amdgcn_mfma_f32_16x16x32_bf16(aq, bk, z[j], 0, 0, 0);
    }

    float l[4] = {0.f, 0.f, 0.f, 0.f};
    #pragma unroll
    for (int j = 0; j < 4; ++j) {
        const int col = 16 * j + cg;
        #pragma unroll
        for (int r = 0; r < 4; ++r) {
            const float e = exp2f(s[j][r]);
            l[r] += e;
            lp[rbase + r][col] = f2bf(e);
        }
    }
    #pragma unroll
    for (int st = 1; st < 16; st <<= 1) {
        #pragma unroll
        for (int r = 0; r < 4; ++r) l[r] += __shfl_xor(l[r], st);
    }
    float linv[4];
    #pragma unroll
    for (int r = 0; r < 4; ++r) linv[r] = 1.f / l[r];
    __syncthreads();

    #pragma unroll
    for (int n = 0; n < 2; ++n) {
        floatx4 o = {0, 0, 0, 0};
        #pragma unroll
        for (int kk = 0; kk < 2; ++kk) {
            short8 ap = *(const short8*)&lp[16 * w + cg][kk * 32 + rg * 8];
            short8 bv = *(const short8*)&lvt[16 * n + cg][kk * 32 + rg * 8];
            o = __builtin_amdgcn_mfma_f32_16x16x32_bf16(ap, bv, o, 0, 0, 0);
        }
        #pragma unroll
        for (int r = 0; r < 4; ++r) {
            const int row = rbase + r;
            if (row < NTOK)
                outa[((size_t)b * NTOK + row) * CDIM + h * HD + n * 16 + cg] =
                    f2bf(o[r] * linv[r]);
        }
    }
}

// =====================================================================
// Kernel 3: out = a @ wpbf^T + proj_b; r3 counted-vmcnt pipeline
// =====================================================================
__global__ __launch_bounds__(256) void proj_kernel(
    const unsigned short* __restrict__ a, const unsigned short* __restrict__ b,
    const float* __restrict__ bias, float* __restrict__ out)
{
    __shared__ __align__(16) unsigned short lA[3][128 * 32];
    __shared__ __align__(16) unsigned short lB[3][128 * 32];

    const int tid = threadIdx.x;
    const int lane = tid & 63, w = tid >> 6;

    const int bid = blockIdx.x;
    const int wg = (bid & 7) * 294 + (bid >> 3);
    const int tN = (wg % 3) * 128;
    const int tM = (wg / 3) * 128;

    const int X = (lane << 4) ^ (((lane >> 3) & 7) << 4);
    const int srow = (w << 5) + (X >> 6);
    const int scol = (X & 63) >> 1;
    const unsigned short* gA = a + (size_t)(tM + srow) * CDIM + scol;
    const unsigned short* gB = b + (size_t)(tN + srow) * CDIM + scol;

    const int wm = (w & 1) << 6, wn = (w >> 1) << 6;
    const int cg = lane & 15, rg = lane >> 4;

    floatx4 acc[4][4];
    #pragma unroll
    for (int i = 0; i < 4; ++i)
        #pragma unroll
        for (int j = 0; j < 4; ++j) acc[i][j] = (floatx4){0.f, 0.f, 0.f, 0.f};

    int offA[4], offB[4];
    #pragma unroll
    for (int i = 0; i < 4; ++i) {
        const int rowA = wm + 16 * i + cg;
        const int sA = (rowA << 6) + (rg << 4);
        offA[i] = sA ^ (((sA >> 7) & 7) << 4);
        const int rowB = wn + 16 * i + cg;
        const int sB = (rowB << 6) + (rg << 4);
        offB[i] = sB ^ (((sB >> 7) & 7) << 4);
    }

    #define STAGE_P(BUF, K0) do {                                          \
        unsigned short* _lAb = &lA[(BUF)][w << 10];                        \
        unsigned short* _lBb = &lB[(BUF)][w << 10];                        \
        gload16(gA + (K0),              _lAb);                             \
        gload16(gA + (K0) + 16 * CDIM,  _lAb + 512);                       \
        gload16(gB + (K0),              _lBb);                             \
        gload16(gB + (K0) + 16 * CDIM,  _lBb + 512);                       \
    } while (0)

    STAGE_P(0, 0);
    STAGE_P(1, 32);

    #pragma unroll
    for (int t = 0; t < 12; ++t) {
        if (t < 11) asm volatile("s_waitcnt vmcnt(4)" ::: "memory");
        else        asm volatile("s_waitcnt vmcnt(0)" ::: "memory");
        __builtin_amdgcn_s_barrier();
        __builtin_amdgcn_sched_barrier(0);

        const int bufb = (t % 3) * 8192;
        short8 af[4], bfr[4];
        #pragma unroll
        for (int i = 0; i < 4; ++i)
            af[i] = *(const short8*)((const char*)lA + bufb + offA[i]);
        #pragma unroll
        for (int j = 0; j < 4; ++j)
            bfr[j] = *(const short8*)((const char*)lB + bufb + offB[j]);

        if (t < 10) STAGE_P((t + 2) % 3, (t + 2) * 32);

        __builtin_amdgcn_s_setprio(1);
        #pragma unroll
        for (int i = 0; i < 4; ++i)
            #pragma unroll
            for (int j = 0; j < 4; ++j)
                acc[i][j] = __builtin_amdgcn_mfma_f32_16x16x32_bf16(af[i], bfr[j], acc[i][j], 0, 0, 0);
        __builtin_amdgcn_s_setprio(0);
    }
    #undef STAGE_P

    const int r0 = tM + wm + (rg << 2);
    #pragma unroll
    for (int j = 0; j < 4; ++j) {
        const int col = tN + wn + 16 * j + cg;
        const float bv = bias[col];
        #pragma unroll
        for (int i = 0; i < 4; ++i) {
            #pragma unroll
            for (int r = 0; r < 4; ++r) {
                const int row = r0 + 16 * i + r;
                out[(size_t)row * CDIM + col] = acc[i][j][r] + bv;
            }
        }
    }
}

// =====================================================================
extern "C" void kernel_launch(void* const* d_in, const int* in_sizes, int n_in,
                              void* d_out, int out_size, void* d_ws, size_t ws_size,
                              hipStream_t stream) {
    const float* x      = (const float*)d_in[0];
    const float* mask   = (const float*)d_in[1];
    const float* qkv_w  = (const float*)d_in[2];
    const float* qkv_b  = (const float*)d_in[3];
    const float* proj_w = (const float*)d_in[4];
    const float* proj_b = (const float*)d_in[5];
    const float* rpb    = (const float*)d_in[6];
    float* out = (float*)d_out;

    unsigned short* ws_qkv  = (unsigned short*)d_ws;                        // 3*B*H*N*hd
    unsigned short* xbf     = ws_qkv + (size_t)3 * BWIN * HNUM * NTOK * HD; // M*C (aliased)
    unsigned short* ws_attn = xbf;   // x_bf16 dead once qkv_kernel completes
    unsigned short* wqbf    = xbf + (size_t)MTOT * CDIM;                    // 3*C*C
    unsigned short* wpbf    = wqbf + (size_t)3 * CDIM * CDIM;               // C*C
    float* cbias            = (float*)(wpbf + (size_t)CDIM * CDIM);        // 64*12*4096 f32

    convert_kernel<<<XBLK + WQBLK + WPBLK, 256, 0, stream>>>(x, qkv_w, proj_w, xbf, wqbf, wpbf);
    bias_kernel<<<dim3(64, HNUM), 256, 0, stream>>>(mask, rpb, cbias);
    qkv_kernel<<<3528, 512, 0, stream>>>(xbf, wqbf, qkv_b, ws_qkv);
    attn_kernel<<<24576, 256, 0, stream>>>(ws_qkv, cbias, ws_attn);
    proj_kernel<<<2352, 256, 0, stream>>>(ws_attn, wpbf, proj_b, out);
}

// Round 11
// 568.761 us; speedup vs baseline: 1.0156x; 1.0156x over previous
//
#include <hip/hip_runtime.h>
#include <stdint.h>
#include <stddef.h>

// ---- problem constants ----
#define BWIN 2048
#define NTOK 49
#define CDIM 384
#define HNUM 12
#define HD   32
#define MTOT (BWIN * NTOK)          // 100352 rows = 392 * 256
#define LOG2E 1.4426950408889634f
// q scale folded with log2(e): logits come out of MFMA in log2 domain
#define QSCALE ((float)(0.17677669529663687 * 1.4426950408889634))

typedef __attribute__((ext_vector_type(8))) short short8;   // 8 bf16 (4 VGPRs)
typedef __attribute__((ext_vector_type(4))) float floatx4;  // MFMA acc

__device__ __forceinline__ unsigned short f2bf(float f) {
    union { float f; unsigned u; } v; v.f = f;
    unsigned u = v.u;
    u = u + 0x7fffu + ((u >> 16) & 1u);   // round-to-nearest-even
    return (unsigned short)(u >> 16);
}

// async global->LDS, 16 B per lane; LDS dest = wave-uniform base + lane*16
__device__ __forceinline__ void gload16(const void* g, void* l) {
    __builtin_amdgcn_global_load_lds(
        (const __attribute__((address_space(1))) void*)g,
        (__attribute__((address_space(3))) void*)l, 16, 0, 0);
}

// =====================================================================
// Kernel 0: fused fp32->bf16 pre-convert (x, qkv_w, proj_w) + bias table
// (one launch instead of two; block ranges dispatch the two jobs)
// =====================================================================
#define XBLK  18816   // 100352*384 / 2048
#define WQBLK 216     // 3*384*384 / 2048
#define WPBLK 72      // 384*384   / 2048
#define CVTBLK (XBLK + WQBLK + WPBLK)   // 19104
#define BIASBLK 768                      // 64 * 12
__global__ __launch_bounds__(256) void convert_bias_kernel(
    const float* __restrict__ x, const float* __restrict__ wq,
    const float* __restrict__ wp, const float* __restrict__ mask,
    const float* __restrict__ rpb,
    unsigned short* __restrict__ xbf, unsigned short* __restrict__ wqbf,
    unsigned short* __restrict__ wpbf, float* __restrict__ cb)
{
    const int bid = blockIdx.x;
    const int tid = threadIdx.x;
    if (bid < CVTBLK) {
        const float* src; unsigned short* dst; size_t base;
        if (bid < XBLK)              { src = x;  dst = xbf;  base = (size_t)bid * 2048; }
        else if (bid < XBLK + WQBLK) { src = wq; dst = wqbf; base = (size_t)(bid - XBLK) * 2048; }
        else                         { src = wp; dst = wpbf; base = (size_t)(bid - XBLK - WQBLK) * 2048; }
        const size_t i = base + (size_t)tid * 8;
        float4 a = *(const float4*)(src + i);
        float4 b = *(const float4*)(src + i + 4);
        unsigned short o[8] = {f2bf(a.x), f2bf(a.y), f2bf(a.z), f2bf(a.w),
                               f2bf(b.x), f2bf(b.y), f2bf(b.z), f2bf(b.w)};
        *(uint4*)(dst + i) = *(uint4*)o;
        return;
    }
    // ---- bias-table job: cb in MFMA accumulator fragment order ----
    const int e = bid - CVTBLK;          // [0, 768)
    const int bm = e & 63, h = e >> 6;
    const int w = tid >> 6, lane = tid & 63;
    const int cg = lane & 15, rg = lane >> 4;
    const int rbase = 16 * w + (rg << 2);
    const float* mk = mask + (size_t)bm * (NTOK * NTOK);
    float o[16];
    #pragma unroll
    for (int j = 0; j < 4; ++j) {
        const int col = 16 * j + cg;
        const bool vc = col < NTOK;
        int yj = 0, xj = 0;
        if (vc) { yj = col / 7; xj = col - yj * 7; }
        #pragma unroll
        for (int r = 0; r < 4; ++r) {
            const int row = rbase + r;
            float v = -1e30f;
            if (vc && row < NTOK) {
                const int yi = row / 7, xi = row - yi * 7;
                const int rel = (yi - yj + 6) * 13 + (xi - xj + 6);
                v = (rpb[rel * HNUM + h] + mk[row * NTOK + col]) * LOG2E;
            }
            o[4 * j + r] = v;
        }
    }
    float* dst = cb + ((size_t)bm * HNUM + h) * 4096 + (size_t)tid * 16;
    #pragma unroll
    for (int j = 0; j < 4; ++j)
        *(float4*)(dst + 4 * j) = *(const float4*)(o + 4 * j);
}

// =====================================================================
// Kernel 1: qkv = xbf @ wqbf^T + qkv_b -> scattered bf16 [3][B][H][N][hd]
// r10 verified-best: BM=256 x BN=128, 512 threads (8 waves, 4Mx2N),
// XCD-chunked swizzle + LDS XOR swizzle + 3-buffer counted-vmcnt
// pipeline (steady vmcnt(3), raw barriers, setprio). FROZEN.
// =====================================================================
__global__ __launch_bounds__(512) void qkv_kernel(
    const unsigned short* __restrict__ a, const unsigned short* __restrict__ b,
    const float* __restrict__ bias, unsigned short* __restrict__ outq)
{
    __shared__ __align__(16) unsigned short lA[3][256 * 32];   // 16KB/buf
    __shared__ __align__(16) unsigned short lB[3][128 * 32];   // 8KB/buf

    const int tid = threadIdx.x;
    const int lane = tid & 63, w = tid >> 6;     // w in [0,8)

    // XCD-chunked swizzle: 3528 blocks, 3528/8 = 441 per XCD (exact)
    const int bid = blockIdx.x;
    const int wg = (bid & 7) * 441 + (bid >> 3);
    const int tN = (wg % 9) * 128;
    const int tM = (wg / 9) * 256;

    const int X = (lane << 4) ^ (((lane >> 3) & 7) << 4);
    const int scol = (X & 63) >> 1;
    const int srowA = (w << 5) + (X >> 6);
    const unsigned short* gA = a + (size_t)(tM + srowA) * CDIM + scol;
    const int srowB = (w << 4) + (X >> 6);
    const unsigned short* gB = b + (size_t)(tN + srowB) * CDIM + scol;

    const int wm = (w & 3) << 6;
    const int wn = (w >> 2) << 6;
    const int cg = lane & 15, rg = lane >> 4;

    floatx4 acc[4][4];
    #pragma unroll
    for (int i = 0; i < 4; ++i)
        #pragma unroll
        for (int j = 0; j < 4; ++j) acc[i][j] = (floatx4){0.f, 0.f, 0.f, 0.f};

    int offA[4], offB[4];
    #pragma unroll
    for (int i = 0; i < 4; ++i) {
        const int rowA = wm + 16 * i + cg;
        const int sA = (rowA << 6) + (rg << 4);
        offA[i] = sA ^ (((sA >> 7) & 7) << 4);
        const int rowB = wn + 16 * i + cg;
        const int sB = (rowB << 6) + (rg << 4);
        offB[i] = sB ^ (((sB >> 7) & 7) << 4);
    }

    #define STAGE_Q(BUF, K0) do {                                          \
        unsigned short* _lAb = &lA[(BUF)][w << 10];                        \
        unsigned short* _lBb = &lB[(BUF)][w << 9];                         \
        gload16(gA + (K0),              _lAb);                             \
        gload16(gA + (K0) + 16 * CDIM,  _lAb + 512);                       \
        gload16(gB + (K0),              _lBb);                             \
    } while (0)

    STAGE_Q(0, 0);
    STAGE_Q(1, 32);

    #pragma unroll
    for (int t = 0; t < 12; ++t) {
        if (t < 11) asm volatile("s_waitcnt vmcnt(3)" ::: "memory");
        else        asm volatile("s_waitcnt vmcnt(0)" ::: "memory");
        __builtin_amdgcn_s_barrier();
        __builtin_amdgcn_sched_barrier(0);

        const int bufA = (t % 3) * 16384;
        const int bufB = (t % 3) * 8192;
        short8 af[4], bfr[4];
        #pragma unroll
        for (int i = 0; i < 4; ++i)
            af[i] = *(const short8*)((const char*)lA + bufA + offA[i]);
        #pragma unroll
        for (int j = 0; j < 4; ++j)
            bfr[j] = *(const short8*)((const char*)lB + bufB + offB[j]);

        if (t < 10) STAGE_Q((t + 2) % 3, (t + 2) * 32);

        __builtin_amdgcn_s_setprio(1);
        #pragma unroll
        for (int i = 0; i < 4; ++i)
            #pragma unroll
            for (int j = 0; j < 4; ++j)
                acc[i][j] = __builtin_amdgcn_mfma_f32_16x16x32_bf16(af[i], bfr[j], acc[i][j], 0, 0, 0);
        __builtin_amdgcn_s_setprio(0);
    }
    #undef STAGE_Q

    const int r0 = tM + wm + (rg << 2);
    float bv[4], sc[4];
    size_t cjo[4];
    #pragma unroll
    for (int j = 0; j < 4; ++j) {
        const int col = tN + wn + 16 * j + cg;
        bv[j] = bias[col];
        const int which = col / CDIM;
        const int rem = col - which * CDIM;
        const int h = rem >> 5, d = rem & 31;
        sc[j] = (which == 0) ? QSCALE : 1.0f;
        cjo[j] = (size_t)which * (BWIN * HNUM * NTOK * HD)
               + (size_t)h * (NTOK * HD) + d;
    }
    #pragma unroll
    for (int i = 0; i < 4; ++i) {
        #pragma unroll
        for (int r = 0; r < 4; ++r) {
            const int row = r0 + 16 * i + r;
            const int bb = row / NTOK;
            const int n = row - bb * NTOK;
            const size_t ro = (size_t)bb * (HNUM * NTOK * HD) + (size_t)n * HD;
            #pragma unroll
            for (int j = 0; j < 4; ++j)
                outq[cjo[j] + ro] = f2bf((acc[i][j][r] + bv[j]) * sc[j]);
        }
    }
}

// =====================================================================
// Kernel 2: MFMA attention — LDS lifetime aliasing: lp overlays the dead
// lq/lk region (strides unchanged -> same bank behavior). LDS 24->14.9KB
// lifts the residency cap 6 -> 8 blocks/CU (wave-limit). One added
// barrier protects the aliased region between QK^T reads and lp writes.
// XCD-locality decode kept (neutral, harmless).
// =====================================================================
__global__ __launch_bounds__(256, 8) void attn_kernel(
    const unsigned short* __restrict__ qkv, const float* __restrict__ cb,
    unsigned short* __restrict__ outa)
{
    // pool layout (bytes):
    //   lq  [64][40] u16 @ 0      (5120)   dead after QK^T fragment reads
    //   lk  [64][40] u16 @ 5120   (5120)   dead after QK^T fragment reads
    //   lvt [32][72] u16 @ 10240  (4608)   live until PV
    //   lp  [64][72] u16 @ 0      (9216)   born after QK^T (aliases lq+lk)
    __shared__ __align__(16) char pool[14848];
    unsigned short (*lq)[40]  = (unsigned short (*)[40])(pool);
    unsigned short (*lk)[40]  = (unsigned short (*)[40])(pool + 5120);
    unsigned short (*lvt)[72] = (unsigned short (*)[72])(pool + 10240);
    unsigned short (*lp)[72]  = (unsigned short (*)[72])(pool);

    const int bid = blockIdx.x;
    const int xcd = bid & 7;
    const int u = (bid >> 3) & 7;
    const int t2 = bid >> 6;
    const int h = t2 % 12;
    const int v = t2 / 12;
    const int b = u + 8 * xcd + 64 * v;

    const int tid = threadIdx.x;
    const size_t WHICH = (size_t)BWIN * HNUM * NTOK * HD;
    const size_t base = ((size_t)b * HNUM + h) * (NTOK * HD);

    // issue cb fragment loads early (independent of LDS staging)
    const float* cbp = cb + ((size_t)(b & 63) * HNUM + h) * 4096 + (size_t)tid * 16;
    floatx4 z[4];
    #pragma unroll
    for (int j = 0; j < 4; ++j) z[j] = *(const floatx4*)(cbp + 4 * j);

    // phase 0: zero pads, stage Q/K into LDS, V into registers
    for (int e = tid; e < 1152; e += 256)
        ((unsigned*)&lvt[0][0])[e] = 0u;
    if (tid < 240) {
        const int r = 49 + (tid >> 4), c = (tid & 15) * 2;
        *(unsigned*)&lq[r][c] = 0u;
        *(unsigned*)&lk[r][c] = 0u;
    }
    uint4 vreg;
    if (tid < 196) {
        const int n = tid >> 2, d = (tid & 3) * 8;
        *(uint4*)&lq[n][d] = *(const uint4*)(qkv + base + tid * 8);
        *(uint4*)&lk[n][d] = *(const uint4*)(qkv + base + WHICH + tid * 8);
        vreg = *(const uint4*)(qkv + base + 2 * WHICH + tid * 8);
    }
    __syncthreads();

    // phase 1: V transpose write (overlaps QK compute of other waves)
    if (tid < 196) {
        const int n = tid >> 2, d0 = (tid & 3) * 8;
        const unsigned short* vp = (const unsigned short*)&vreg;
        #pragma unroll
        for (int jj = 0; jj < 8; ++jj)
            lvt[d0 + jj][n] = vp[jj];
    }

    const int w = tid >> 6, lane = tid & 63;
    const int cg = lane & 15;
    const int rg = lane >> 4;
    const int rbase = 16 * w + rg * 4;

    short8 aq = *(const short8*)&lq[16 * w + cg][rg * 8];
    floatx4 s[4];
    #pragma unroll
    for (int j = 0; j < 4; ++j) {
        short8 bk = *(const short8*)&lk[16 * j + cg][rg * 8];
        s[j] = __builtin_amdgcn_mfma_f32_16x16x32_bf16(aq, bk, z[j], 0, 0, 0);
    }

    // all waves' lq/lk fragment reads are complete at this barrier;
    // the aliased lp region may now be overwritten
    __syncthreads();

    // softmax: logits already in log2 domain, pads are -1e30 -> exp2 = 0
    float l[4] = {0.f, 0.f, 0.f, 0.f};
    #pragma unroll
    for (int j = 0; j < 4; ++j) {
        const int col = 16 * j + cg;
        #pragma unroll
        for (int r = 0; r < 4; ++r) {
            const float e = exp2f(s[j][r]);
            l[r] += e;
            lp[rbase + r][col] = f2bf(e);
        }
    }
    #pragma unroll
    for (int st = 1; st < 16; st <<= 1) {
        #pragma unroll
        for (int r = 0; r < 4; ++r) l[r] += __shfl_xor(l[r], st);
    }
    float linv[4];
    #pragma unroll
    for (int r = 0; r < 4; ++r) linv[r] = 1.f / l[r];
    __syncthreads();

    #pragma unroll
    for (int n = 0; n < 2; ++n) {
        floatx4 o = {0, 0, 0, 0};
        #pragma unroll
        for (int kk = 0; kk < 2; ++kk) {
            short8 ap = *(const short8*)&lp[16 * w + cg][kk * 32 + rg * 8];
            short8 bv = *(const short8*)&lvt[16 * n + cg][kk * 32 + rg * 8];
            o = __builtin_amdgcn_mfma_f32_16x16x32_bf16(ap, bv, o, 0, 0, 0);
        }
        #pragma unroll
        for (int r = 0; r < 4; ++r) {
            const int row = rbase + r;
            if (row < NTOK)
                outa[((size_t)b * NTOK + row) * CDIM + h * HD + n * 16 + cg] =
                    f2bf(o[r] * linv[r]);
        }
    }
}

// =====================================================================
// Kernel 3: out = a @ wpbf^T + proj_b; r3 counted-vmcnt pipeline
// =====================================================================
__global__ __launch_bounds__(256) void proj_kernel(
    const unsigned short* __restrict__ a, const unsigned short* __restrict__ b,
    const float* __restrict__ bias, float* __restrict__ out)
{
    __shared__ __align__(16) unsigned short lA[3][128 * 32];
    __shared__ __align__(16) unsigned short lB[3][128 * 32];

    const int tid = threadIdx.x;
    const int lane = tid & 63, w = tid >> 6;

    const int bid = blockIdx.x;
    const int wg = (bid & 7) * 294 + (bid >> 3);
    const int tN = (wg % 3) * 128;
    const int tM = (wg / 3) * 128;

    const int X = (lane << 4) ^ (((lane >> 3) & 7) << 4);
    const int srow = (w << 5) + (X >> 6);
    const int scol = (X & 63) >> 1;
    const unsigned short* gA = a + (size_t)(tM + srow) * CDIM + scol;
    const unsigned short* gB = b + (size_t)(tN + srow) * CDIM + scol;

    const int wm = (w & 1) << 6, wn = (w >> 1) << 6;
    const int cg = lane & 15, rg = lane >> 4;

    floatx4 acc[4][4];
    #pragma unroll
    for (int i = 0; i < 4; ++i)
        #pragma unroll
        for (int j = 0; j < 4; ++j) acc[i][j] = (floatx4){0.f, 0.f, 0.f, 0.f};

    int offA[4], offB[4];
    #pragma unroll
    for (int i = 0; i < 4; ++i) {
        const int rowA = wm + 16 * i + cg;
        const int sA = (rowA << 6) + (rg << 4);
        offA[i] = sA ^ (((sA >> 7) & 7) << 4);
        const int rowB = wn + 16 * i + cg;
        const int sB = (rowB << 6) + (rg << 4);
        offB[i] = sB ^ (((sB >> 7) & 7) << 4);
    }

    #define STAGE_P(BUF, K0) do {                                          \
        unsigned short* _lAb = &lA[(BUF)][w << 10];                        \
        unsigned short* _lBb = &lB[(BUF)][w << 10];                        \
        gload16(gA + (K0),              _lAb);                             \
        gload16(gA + (K0) + 16 * CDIM,  _lAb + 512);                       \
        gload16(gB + (K0),              _lBb);                             \
        gload16(gB + (K0) + 16 * CDIM,  _lBb + 512);                       \
    } while (0)

    STAGE_P(0, 0);
    STAGE_P(1, 32);

    #pragma unroll
    for (int t = 0; t < 12; ++t) {
        if (t < 11) asm volatile("s_waitcnt vmcnt(4)" ::: "memory");
        else        asm volatile("s_waitcnt vmcnt(0)" ::: "memory");
        __builtin_amdgcn_s_barrier();
        __builtin_amdgcn_sched_barrier(0);

        const int bufb = (t % 3) * 8192;
        short8 af[4], bfr[4];
        #pragma unroll
        for (int i = 0; i < 4; ++i)
            af[i] = *(const short8*)((const char*)lA + bufb + offA[i]);
        #pragma unroll
        for (int j = 0; j < 4; ++j)
            bfr[j] = *(const short8*)((const char*)lB + bufb + offB[j]);

        if (t < 10) STAGE_P((t + 2) % 3, (t + 2) * 32);

        __builtin_amdgcn_s_setprio(1);
        #pragma unroll
        for (int i = 0; i < 4; ++i)
            #pragma unroll
            for (int j = 0; j < 4; ++j)
                acc[i][j] = __builtin_amdgcn_mfma_f32_16x16x32_bf16(af[i], bfr[j], acc[i][j], 0, 0, 0);
        __builtin_amdgcn_s_setprio(0);
    }
    #undef STAGE_P

    const int r0 = tM + wm + (rg << 2);
    #pragma unroll
    for (int j = 0; j < 4; ++j) {
        const int col = tN + wn + 16 * j + cg;
        const float bv = bias[col];
        #pragma unroll
        for (int i = 0; i < 4; ++i) {
            #pragma unroll
            for (int r = 0; r < 4; ++r) {
                const int row = r0 + 16 * i + r;
                out[(size_t)row * CDIM + col] = acc[i][j][r] + bv;
            }
        }
    }
}

// =====================================================================
extern "C" void kernel_launch(void* const* d_in, const int* in_sizes, int n_in,
                              void* d_out, int out_size, void* d_ws, size_t ws_size,
                              hipStream_t stream) {
    const float* x      = (const float*)d_in[0];
    const float* mask   = (const float*)d_in[1];
    const float* qkv_w  = (const float*)d_in[2];
    const float* qkv_b  = (const float*)d_in[3];
    const float* proj_w = (const float*)d_in[4];
    const float* proj_b = (const float*)d_in[5];
    const float* rpb    = (const float*)d_in[6];
    float* out = (float*)d_out;

    unsigned short* ws_qkv  = (unsigned short*)d_ws;                        // 3*B*H*N*hd
    unsigned short* xbf     = ws_qkv + (size_t)3 * BWIN * HNUM * NTOK * HD; // M*C (aliased)
    unsigned short* ws_attn = xbf;   // x_bf16 dead once qkv_kernel completes
    unsigned short* wqbf    = xbf + (size_t)MTOT * CDIM;                    // 3*C*C
    unsigned short* wpbf    = wqbf + (size_t)3 * CDIM * CDIM;               // C*C
    float* cbias            = (float*)(wpbf + (size_t)CDIM * CDIM);        // 64*12*4096 f32

    convert_bias_kernel<<<CVTBLK + BIASBLK, 256, 0, stream>>>(
        x, qkv_w, proj_w, mask, rpb, xbf, wqbf, wpbf, cbias);
    qkv_kernel<<<3528, 512, 0, stream>>>(xbf, wqbf, qkv_b, ws_qkv);
    attn_kernel<<<24576, 256, 0, stream>>>(ws_qkv, cbias, ws_attn);
    proj_kernel<<<2352, 256, 0, stream>>>(ws_attn, wpbf, proj_b, out);
}